// Round 11
// baseline (471.798 us; speedup 1.0000x reference)
//
#include <hip/hip_runtime.h>
#include <hip/hip_bf16.h>

// RGCN encoder: N=100000, E=128, R=9, L=3, NE=640000. Only the LAST layer
// matters (reference resets hidden=embeddings each layer).
//   out[n] = sum_{e:dst=n}(W_t h[src]+b_t) + sum_{e:src=n}(W_{t+9} h[dst]+b_{t+9})
// AGGREGATE-FIRST (linearity): out[d] = sum_t W_t * M_t[d] + deg_t(d)*b_t.
// Round-11: records TYPE-SORTED within each (node,dir) segment via a
// (node,type)-granular CSR (1.8M-element scan). The aggregation loop then
// needs no per-record type dispatch (round-10's 9-way switch cost ~140us):
// accumulate 2 regs, flush to Mt only at type boundaries (<=9/segment).
// 8-deep record batches: one lane-strided rec load + readlane, 8 gathers in
// flight. Bounds for all 4 nodes of the wave prefetched in one load; deg_t
// falls out of the bounds. MFMA (swapped operands) + deg*b epilogue as r9/r10.

#define E_DIM 128
#define R_REL 9
#define TN 16        // nodes per fused block
#define MT_P 1156    // Mt pitch in ushorts
#define SCB 1024     // elements per scan block
#define NSLICE 96    // edge slices per octant in count/fill

typedef __attribute__((ext_vector_type(8))) short short8v;
typedef __attribute__((ext_vector_type(4))) float f32x4;

static __device__ __forceinline__ unsigned short f2bf(float f) {
    union { float f; unsigned u; } v; v.f = f;
    unsigned u = v.u;
    return (unsigned short)((u + 0x7FFFu + ((u >> 16) & 1u)) >> 16);
}
static __device__ __forceinline__ float bf2f(unsigned short h) {
    union { unsigned u; float f; } v; v.u = ((unsigned)h) << 16;
    return v.f;
}

// ---------- fast path ----------

// Combined prep: blocks 0..17 swizzle W (Wt[rel][w][s][c][lane][j] fragment
// order); blocks 18.. convert H fp32 -> bf16 (Hbf).
__global__ __launch_bounds__(256) void prep(
    const float* __restrict__ H, const float* __restrict__ W18,
    unsigned short* __restrict__ Hbf, unsigned short* __restrict__ Wt,
    long total8)
{
    const int tid = threadIdx.x;
    if (blockIdx.x < 18) {
        const int rel = blockIdx.x;
        const float* __restrict__ Wr = W18 + (size_t)rel * E_DIM * E_DIM;
#pragma unroll
        for (int k = 0; k < 8; k++) {
            int f = tid + k * 256;            // 0..2047
            int lane = f & 63;
            int c = (f >> 6) & 1;
            int s = (f >> 7) & 3;
            int w = (f >> 9) & 3;
            int col = w * 32 + c * 16 + (lane & 15);
            int kb = s * 32 + (lane >> 4) * 8;
            short8v v;
#pragma unroll
            for (int j = 0; j < 8; j++)
                v[j] = (short)f2bf(Wr[(size_t)(kb + j) * E_DIM + col]);
            *(short8v*)(Wt + ((size_t)((((rel * 4 + w) * 4 + s) * 2 + c) * 64 + lane)) * 8) = v;
        }
    } else {
        long i = (long)(blockIdx.x - 18) * 256 + tid;
        if (i >= total8) return;
        const float4* src = (const float4*)(H + i * 8);
        float4 a = src[0], b = src[1];
        short8v o;
        o[0] = (short)f2bf(a.x); o[1] = (short)f2bf(a.y);
        o[2] = (short)f2bf(a.z); o[3] = (short)f2bf(a.w);
        o[4] = (short)f2bf(b.x); o[5] = (short)f2bf(b.y);
        o[6] = (short)f2bf(b.z); o[7] = (short)f2bf(b.w);
        *(short8v*)(Hbf + i * 8) = o;
    }
}

// CSR over n3 = 2*Nn*9 (node,dir,type) segments; key = seg*9+t, seg = d (fwd)
// or Nn+s (bwd). Octant-partitioned by node: counter window 0.9MB, L2-local.
__global__ __launch_bounds__(256) void k_count8(
    const int* __restrict__ esrc, const int* __restrict__ edst,
    const int* __restrict__ etype, int* __restrict__ cnt, int ne, int Nn)
{
    const int oct = blockIdx.x & 7;
    const int slice = blockIdx.x >> 3;
    const int lo = (int)(((long long)oct * Nn) >> 3);
    const int hi = (int)(((long long)(oct + 1) * Nn) >> 3);
    for (int e = slice * 256 + threadIdx.x; e < ne; e += NSLICE * 256) {
        int t = etype[e], s = esrc[e], d = edst[e];
        if (d >= lo && d < hi) atomicAdd(&cnt[d * R_REL + t], 1);
        if (s >= lo && s < hi) atomicAdd(&cnt[(Nn + s) * R_REL + t], 1);
    }
}

// Hierarchical scan, 3 kernels (r5-validated).
__global__ __launch_bounds__(256) void k_scan_part(
    const int* __restrict__ cnt, int* __restrict__ loc,
    int* __restrict__ bsum, int n2)
{
    __shared__ int sh[256];
    const int tid = threadIdx.x;
    const int i0 = blockIdx.x * SCB + tid * 4;
    int v0 = 0, v1 = 0, v2 = 0, v3 = 0;
    if (i0 + 3 < n2) {
        int4 v = *(const int4*)(cnt + i0);
        v0 = v.x; v1 = v.y; v2 = v.z; v3 = v.w;
    } else {
        if (i0 + 0 < n2) v0 = cnt[i0 + 0];
        if (i0 + 1 < n2) v1 = cnt[i0 + 1];
        if (i0 + 2 < n2) v2 = cnt[i0 + 2];
        if (i0 + 3 < n2) v3 = cnt[i0 + 3];
    }
    int t = v0 + v1 + v2 + v3;
    sh[tid] = t;
    __syncthreads();
    for (int o = 1; o < 256; o <<= 1) {
        int x = (tid >= o) ? sh[tid - o] : 0;
        __syncthreads();
        sh[tid] += x;
        __syncthreads();
    }
    int excl = sh[tid] - t;
    if (tid == 255) bsum[blockIdx.x] = sh[255];
    int p0 = excl, p1 = p0 + v0, p2 = p1 + v1, p3 = p2 + v2;
    if (i0 + 3 < n2) {
        *(int4*)(loc + i0) = make_int4(p0, p1, p2, p3);
    } else {
        if (i0 + 0 < n2) loc[i0 + 0] = p0;
        if (i0 + 1 < n2) loc[i0 + 1] = p1;
        if (i0 + 2 < n2) loc[i0 + 2] = p2;
        if (i0 + 3 < n2) loc[i0 + 3] = p3;
    }
}

__global__ __launch_bounds__(256) void k_scan_mid(int* __restrict__ bsum, int nb)
{
    __shared__ int sh[256];
    __shared__ int carry;
    const int tid = threadIdx.x;
    if (tid == 0) carry = 0;
    __syncthreads();
    for (int base = 0; base < nb; base += 256) {
        int i = base + tid;
        int v = (i < nb) ? bsum[i] : 0;
        sh[tid] = v;
        __syncthreads();
        for (int o = 1; o < 256; o <<= 1) {
            int x = (tid >= o) ? sh[tid - o] : 0;
            __syncthreads();
            sh[tid] += x;
            __syncthreads();
        }
        int excl = sh[tid] - v + carry;
        int total = sh[255];
        if (i < nb) bsum[i] = excl;
        __syncthreads();
        if (tid == 0) carry += total;
        __syncthreads();
    }
}

__global__ __launch_bounds__(256) void k_scan_apply(
    const int* __restrict__ loc, const int* __restrict__ bsum,
    int* __restrict__ off, int* __restrict__ cursor, int n2)
{
    const int add = bsum[blockIdx.x];
    const int i0 = blockIdx.x * SCB + threadIdx.x * 4;
    if (i0 + 3 < n2) {
        int4 v = *(const int4*)(loc + i0);
        v.x += add; v.y += add; v.z += add; v.w += add;
        *(int4*)(off + i0) = v;
        *(int4*)(cursor + i0) = v;
    } else {
#pragma unroll
        for (int j = 0; j < 4; j++)
            if (i0 + j < n2) {
                int v = loc[i0 + j] + add;
                off[i0 + j] = v;
                cursor[i0 + j] = v;
            }
    }
}

// rec = (t<<20) | otherNode, written via (node,t) cursor -> records are
// type-grouped within each node segment. Octant-partitioned.
__global__ __launch_bounds__(256) void k_fill8(
    const int* __restrict__ esrc, const int* __restrict__ edst,
    const int* __restrict__ etype, int* __restrict__ cursor,
    unsigned* __restrict__ rec, int ne, int Nn)
{
    const int oct = blockIdx.x & 7;
    const int slice = blockIdx.x >> 3;
    const int lo = (int)(((long long)oct * Nn) >> 3);
    const int hi = (int)(((long long)(oct + 1) * Nn) >> 3);
    for (int e = slice * 256 + threadIdx.x; e < ne; e += NSLICE * 256) {
        int t = etype[e], s = esrc[e], d = edst[e];
        if (d >= lo && d < hi) {
            int p = atomicAdd(&cursor[d * R_REL + t], 1);
            rec[p] = ((unsigned)t << 20) | (unsigned)s;   // fwd msg into d
        }
        if (s >= lo && s < hi) {
            int p2 = atomicAdd(&cursor[(Nn + s) * R_REL + t], 1);
            rec[p2] = ((unsigned)t << 20) | (unsigned)d;  // bwd msg into s
        }
    }
}

// Fused aggregate+GEMM. Block = 16 nodes, 4 waves. Per direction:
//  - wave zeroes its 4 Mt rows (wave-private, no barrier needed)
//  - bounds for all 4 nodes prefetched in one lane-spread load
//    (lane = j*16+t, j=lane>>4, t=lane&15<9); degS written from same
//  - per node: single type-sorted record loop, 8-deep batches (one
//    lane-strided rec load + readlane -> 8 SGPR recs, 8 row gathers in
//    flight), accumulate 2 regs, flush on type-change (wave-uniform, <=9x)
//  - barrier; MFMA acc += Mt @ W[dir] (swapped operands: lane&15 = node,
//    acc reg = 4 consecutive cols); barrier.
// Epilogue: + deg_t*b_t both dirs, single fp32 out store.
__global__ __launch_bounds__(256, 4) void fused_rgcn(
    const unsigned short* __restrict__ Hbf, const unsigned short* __restrict__ Wt,
    const float* __restrict__ B18,
    const int* __restrict__ off3, const int* __restrict__ cur3,
    const unsigned* __restrict__ rec,
    float* __restrict__ out, int Nn)
{
    __shared__ __align__(16) unsigned short Mt[TN][MT_P];
    __shared__ float degS[2][TN][R_REL];

    const int tid = threadIdx.x;
    const int lane = tid & 63;
    const int w = tid >> 6;             // wave id; col slice w*32..w*32+31
    const int lr = lane & 15;
    const int lg = lane >> 4;
    const int n0 = blockIdx.x * TN;

    const short8v* wt8 = (const short8v*)Wt;

    f32x4 acc[2];
    acc[0] = (f32x4){0.f, 0.f, 0.f, 0.f};
    acc[1] = (f32x4){0.f, 0.f, 0.f, 0.f};

#define FLUSH()                                                               \
    do {                                                                      \
        if (cur_t >= 0) {                                                     \
            unsigned pk = ((unsigned)f2bf(ay) << 16) | (unsigned)f2bf(ax);    \
            *(unsigned*)((char*)&Mt[node][0] + cur_t * 256 + lane * 4) = pk;  \
        }                                                                     \
    } while (0)

#define ACC_STEP(rk, vk)                                                      \
    {                                                                         \
        int _t = (rk) >> 20;                                                  \
        if (_t != cur_t) { FLUSH(); cur_t = _t; ax = 0.f; ay = 0.f; }         \
        ax += bf2f((vk).x); ay += bf2f((vk).y);                               \
    }

#pragma unroll 1
    for (int dir = 0; dir < 2; dir++) {
        // Zero this wave's Mt rows (1152 used ushorts per row).
        const short8v z8 = (short8v){0, 0, 0, 0, 0, 0, 0, 0};
#pragma unroll
        for (int rr = 0; rr < 4; rr++) {
            int row = w * 4 + rr;
            *(short8v*)(&Mt[row][(size_t)lane * 8]) = z8;
            *(short8v*)(&Mt[row][(size_t)(lane + 64) * 8]) = z8;
            if (lane < 16) *(short8v*)(&Mt[row][(size_t)(lane + 128) * 8]) = z8;
        }

        // Prefetch bounds for all 4 nodes: lane = jj*16 + tt.
        const int jj = lg, tt = lr;
        const int gnode_j = n0 + w * 4 + jj;
        int blo = 0, bhi = 0;
        if (gnode_j < Nn && tt < R_REL) {
            size_t sb = ((size_t)(dir ? (Nn + gnode_j) : gnode_j)) * R_REL + tt;
            blo = off3[sb];
            bhi = cur3[sb];
            degS[dir][w * 4 + jj][tt] = (float)(bhi - blo);
        }

#pragma unroll 1
        for (int j = 0; j < 4; j++) {
            const int node = w * 4 + j;
            const int st = __shfl(blo, j * 16);
            const int en = __shfl(bhi, j * 16 + 8);

            int cur_t = -1;
            float ax = 0.f, ay = 0.f;
            int i = st;
            for (; i + 8 <= en; i += 8) {
                unsigned rv = rec[i + (lane & 7)];       // lane-strided, 8 recs
                int r0 = __builtin_amdgcn_readlane(rv, 0);
                int r1 = __builtin_amdgcn_readlane(rv, 1);
                int r2 = __builtin_amdgcn_readlane(rv, 2);
                int r3 = __builtin_amdgcn_readlane(rv, 3);
                int r4 = __builtin_amdgcn_readlane(rv, 4);
                int r5 = __builtin_amdgcn_readlane(rv, 5);
                int r6 = __builtin_amdgcn_readlane(rv, 6);
                int r7 = __builtin_amdgcn_readlane(rv, 7);
                ushort2 v0 = *(const ushort2*)(Hbf + (size_t)(r0 & 0xFFFFF) * E_DIM + 2 * lane);
                ushort2 v1 = *(const ushort2*)(Hbf + (size_t)(r1 & 0xFFFFF) * E_DIM + 2 * lane);
                ushort2 v2 = *(const ushort2*)(Hbf + (size_t)(r2 & 0xFFFFF) * E_DIM + 2 * lane);
                ushort2 v3 = *(const ushort2*)(Hbf + (size_t)(r3 & 0xFFFFF) * E_DIM + 2 * lane);
                ushort2 v4 = *(const ushort2*)(Hbf + (size_t)(r4 & 0xFFFFF) * E_DIM + 2 * lane);
                ushort2 v5 = *(const ushort2*)(Hbf + (size_t)(r5 & 0xFFFFF) * E_DIM + 2 * lane);
                ushort2 v6 = *(const ushort2*)(Hbf + (size_t)(r6 & 0xFFFFF) * E_DIM + 2 * lane);
                ushort2 v7 = *(const ushort2*)(Hbf + (size_t)(r7 & 0xFFFFF) * E_DIM + 2 * lane);
                ACC_STEP(r0, v0);
                ACC_STEP(r1, v1);
                ACC_STEP(r2, v2);
                ACC_STEP(r3, v3);
                ACC_STEP(r4, v4);
                ACC_STEP(r5, v5);
                ACC_STEP(r6, v6);
                ACC_STEP(r7, v7);
            }
            for (; i < en; i++) {
                int rk = __builtin_amdgcn_readfirstlane((int)rec[i]);
                ushort2 vk = *(const ushort2*)(Hbf + (size_t)(rk & 0xFFFFF) * E_DIM + 2 * lane);
                ACC_STEP(rk, vk);
            }
            FLUSH();
        }
        __syncthreads();

        // ---- GEMM: acc += Mt @ W[dir group] ----
#pragma unroll 1
        for (int q = 0; q < R_REL; q++) {
            const int rel = dir * R_REL + q;
#pragma unroll
            for (int s = 0; s < 4; s++) {
                short8v b0 = wt8[(size_t)((((rel * 4 + w) * 4 + s) * 2 + 0) * 64) + lane];
                short8v b1 = wt8[(size_t)((((rel * 4 + w) * 4 + s) * 2 + 1) * 64) + lane];
                short8v a = *(const short8v*)(&Mt[lr][q * E_DIM + s * 32 + lg * 8]);
                acc[0] = __builtin_amdgcn_mfma_f32_16x16x32_bf16(b0, a, acc[0], 0, 0, 0);
                acc[1] = __builtin_amdgcn_mfma_f32_16x16x32_bf16(b1, a, acc[1], 0, 0, 0);
            }
        }
        __syncthreads();   // before next dir overwrites Mt
    }

    // ---- epilogue: bias (deg_t * b_t) + store ----
    const int gnode = n0 + lr;
    if (gnode >= Nn) return;
#pragma unroll 1
    for (int dir = 0; dir < 2; dir++) {
#pragma unroll 1
        for (int t = 0; t < R_REL; t++) {
            float dg = degS[dir][lr][t];
            if (dg != 0.f) {
                const float* brow = B18 + (size_t)(dir * R_REL + t) * E_DIM + w * 32 + lg * 4;
                float4 b0 = *(const float4*)(brow);
                float4 b1 = *(const float4*)(brow + 16);
                acc[0][0] += dg * b0.x; acc[0][1] += dg * b0.y;
                acc[0][2] += dg * b0.z; acc[0][3] += dg * b0.w;
                acc[1][0] += dg * b1.x; acc[1][1] += dg * b1.y;
                acc[1][2] += dg * b1.z; acc[1][3] += dg * b1.w;
            }
        }
    }
    float* po = out + (size_t)gnode * E_DIM + w * 32 + lg * 4;
    *(float4*)po = make_float4(acc[0][0], acc[0][1], acc[0][2], acc[0][3]);
    *(float4*)(po + 16) = make_float4(acc[1][0], acc[1][1], acc[1][2], acc[1][3]);
#undef FLUSH
#undef ACC_STEP
}

// ---------- zero-workspace fallback (round-1, validated) ----------

__global__ __launch_bounds__(128) void direct_edge(
    const int* __restrict__ esrc, const int* __restrict__ edst,
    const int* __restrict__ etype,
    const float* __restrict__ H, const float* __restrict__ W2,
    const float* __restrict__ B2, float* __restrict__ out, int ne)
{
    __shared__ float hs[E_DIM];
    __shared__ float hd[E_DIM];
    int e = blockIdx.x;
    if (e >= ne) return;
    int t = etype[e], s = esrc[e], d = edst[e];
    int c = threadIdx.x;
    hs[c] = H[(size_t)s * E_DIM + c];
    hd[c] = H[(size_t)d * E_DIM + c];
    __syncthreads();
    const float* Wf = W2 + (size_t)t * E_DIM * E_DIM;
    const float* Wb = W2 + (size_t)(t + R_REL) * E_DIM * E_DIM;
    float accf = B2[(size_t)t * E_DIM + c];
    float accb = B2[(size_t)(t + R_REL) * E_DIM + c];
#pragma unroll 8
    for (int k = 0; k < E_DIM; k++) {
        accf += hs[k] * Wf[(size_t)k * E_DIM + c];
        accb += hd[k] * Wb[(size_t)k * E_DIM + c];
    }
    atomicAdd(&out[(size_t)d * E_DIM + c], accf);
    atomicAdd(&out[(size_t)s * E_DIM + c], accb);
}

extern "C" void kernel_launch(void* const* d_in, const int* in_sizes, int n_in,
                              void* d_out, int out_size, void* d_ws, size_t ws_size,
                              hipStream_t stream) {
    const int* edge_index = (const int*)d_in[0];   // [2][NE]
    const int* edge_type  = (const int*)d_in[1];   // [NE]
    const float* emb      = (const float*)d_in[2]; // [N][128]
    const float* weights  = (const float*)d_in[3]; // [L][18][128][128]
    const float* biases   = (const float*)d_in[4]; // [L][18][128]
    float* out = (float*)d_out;

    const int NE = in_sizes[1];
    const int Nn = in_sizes[2] / E_DIM;
    const int L  = in_sizes[3] / (2 * R_REL * E_DIM * E_DIM);

    const float* W2 = weights + (size_t)(L - 1) * 2 * R_REL * E_DIM * E_DIM;
    const float* B2 = biases  + (size_t)(L - 1) * 2 * R_REL * E_DIM;

    const int* esrc = edge_index;
    const int* edst = edge_index + NE;

    const int n3 = 2 * Nn * R_REL;                 // (node,dir,type) segments
    const int nb3 = (n3 + SCB - 1) / SCB;

    auto al = [](size_t x) { return (x + 255) & ~(size_t)255; };
    const size_t hbfBytes = al((size_t)Nn * E_DIM * 2);
    const size_t wtBytes  = al((size_t)2 * R_REL * E_DIM * E_DIM * 2);
    const size_t offBytes = al((size_t)n3 * 4);
    const size_t curBytes = al((size_t)n3 * 4);
    const size_t recBytes = al((size_t)2 * NE * 4);
    const size_t bsBytes  = al((size_t)nb3 * 4);
    const size_t need = hbfBytes + wtBytes + offBytes + curBytes + recBytes + bsBytes;

    if (ws_size >= need && Nn < (1 << 20)) {
        char* p = (char*)d_ws;
        unsigned short* Hbf = (unsigned short*)p;        p += hbfBytes;
        unsigned short* Wt  = (unsigned short*)p;        p += wtBytes;
        int* off3           = (int*)p;                   p += offBytes;
        int* cur3           = (int*)p;                   p += curBytes;
        unsigned* rec       = (unsigned*)p;              p += recBytes;
        int* bsum           = (int*)p;

        const long total8 = (long)Nn * (E_DIM / 8);
        const int hblocks = (int)((total8 + 255) / 256);

        hipMemsetAsync(off3, 0, (size_t)n3 * 4, stream);
        prep<<<18 + hblocks, 256, 0, stream>>>(emb, W2, Hbf, Wt, total8);
        k_count8<<<8 * NSLICE, 256, 0, stream>>>(esrc, edst, edge_type, off3, NE, Nn);
        k_scan_part<<<nb3, 256, 0, stream>>>(off3, cur3, bsum, n3);
        k_scan_mid<<<1, 256, 0, stream>>>(bsum, nb3);
        k_scan_apply<<<nb3, 256, 0, stream>>>(cur3, bsum, off3, cur3, n3);
        k_fill8<<<8 * NSLICE, 256, 0, stream>>>(esrc, edst, edge_type,
                                                cur3, rec, NE, Nn);

        fused_rgcn<<<(Nn + TN - 1) / TN, 256, 0, stream>>>(
            Hbf, Wt, B2, off3, cur3, rec, out, Nn);
        return;
    }

    // Fallback: direct per-edge GEMV with atomics.
    hipMemsetAsync(d_out, 0, (size_t)Nn * E_DIM * sizeof(float), stream);
    direct_edge<<<NE, 128, 0, stream>>>(esrc, edst, edge_type, emb, W2, B2, out, NE);
}

// Round 12
// 414.427 us; speedup vs baseline: 1.1384x; 1.1384x over previous
//
#include <hip/hip_runtime.h>
#include <hip/hip_bf16.h>

// RGCN encoder: N=100000, E=128, R=9, L=3, NE=640000. Only the LAST layer
// matters (reference resets hidden=embeddings each layer).
//   out[n] = sum_{e:dst=n}(W_t h[src]+b_t) + sum_{e:src=n}(W_{t+9} h[dst]+b_{t+9})
// AGGREGATE-FIRST (linearity): out[d] = sum_t W_t * M_t[d] + deg_t(d)*b_t.
// Round-12: r11's aggregation was serialized by the per-record register
// accumulator chain + tiny (6.4-record) type-runs. Fix: wave streams its 4
// nodes' records as ONE contiguous range (node = 3 scalar index compares,
// type from the record), accumulating via independent bf16 LDS
// read-modify-writes -- no register carry, 8 gathers in flight per batch.
// CSR (node,type)-sorted as r11. MFMA (swapped operands) + deg*b epilogue.

#define E_DIM 128
#define R_REL 9
#define TN 16        // nodes per fused block
#define MT_P 1156    // Mt pitch in ushorts (578 words; 578%32=2 -> frag reads ok)
#define SCB 1024     // elements per scan block
#define NSLICE 96    // edge slices per octant in count/fill

typedef __attribute__((ext_vector_type(8))) short short8v;
typedef __attribute__((ext_vector_type(4))) float f32x4;

static __device__ __forceinline__ unsigned short f2bf(float f) {
    union { float f; unsigned u; } v; v.f = f;
    unsigned u = v.u;
    return (unsigned short)((u + 0x7FFFu + ((u >> 16) & 1u)) >> 16);
}
static __device__ __forceinline__ float bf2f(unsigned short h) {
    union { unsigned u; float f; } v; v.u = ((unsigned)h) << 16;
    return v.f;
}

// ---------- fast path ----------

// Combined prep: blocks 0..17 swizzle W into MFMA fragment order; blocks 18..
// convert H fp32 -> bf16.
__global__ __launch_bounds__(256) void prep(
    const float* __restrict__ H, const float* __restrict__ W18,
    unsigned short* __restrict__ Hbf, unsigned short* __restrict__ Wt,
    long total8)
{
    const int tid = threadIdx.x;
    if (blockIdx.x < 18) {
        const int rel = blockIdx.x;
        const float* __restrict__ Wr = W18 + (size_t)rel * E_DIM * E_DIM;
#pragma unroll
        for (int k = 0; k < 8; k++) {
            int f = tid + k * 256;            // 0..2047
            int lane = f & 63;
            int c = (f >> 6) & 1;
            int s = (f >> 7) & 3;
            int w = (f >> 9) & 3;
            int col = w * 32 + c * 16 + (lane & 15);
            int kb = s * 32 + (lane >> 4) * 8;
            short8v v;
#pragma unroll
            for (int j = 0; j < 8; j++)
                v[j] = (short)f2bf(Wr[(size_t)(kb + j) * E_DIM + col]);
            *(short8v*)(Wt + ((size_t)((((rel * 4 + w) * 4 + s) * 2 + c) * 64 + lane)) * 8) = v;
        }
    } else {
        long i = (long)(blockIdx.x - 18) * 256 + tid;
        if (i >= total8) return;
        const float4* src = (const float4*)(H + i * 8);
        float4 a = src[0], b = src[1];
        short8v o;
        o[0] = (short)f2bf(a.x); o[1] = (short)f2bf(a.y);
        o[2] = (short)f2bf(a.z); o[3] = (short)f2bf(a.w);
        o[4] = (short)f2bf(b.x); o[5] = (short)f2bf(b.y);
        o[6] = (short)f2bf(b.z); o[7] = (short)f2bf(b.w);
        *(short8v*)(Hbf + i * 8) = o;
    }
}

// CSR over n3 = 2*Nn*9 (node,dir,type) segments; key = seg*9+t, seg = d (fwd)
// or Nn+s (bwd). Octant-partitioned by node: counter window L2-local.
__global__ __launch_bounds__(256) void k_count8(
    const int* __restrict__ esrc, const int* __restrict__ edst,
    const int* __restrict__ etype, int* __restrict__ cnt, int ne, int Nn)
{
    const int oct = blockIdx.x & 7;
    const int slice = blockIdx.x >> 3;
    const int lo = (int)(((long long)oct * Nn) >> 3);
    const int hi = (int)(((long long)(oct + 1) * Nn) >> 3);
    for (int e = slice * 256 + threadIdx.x; e < ne; e += NSLICE * 256) {
        int t = etype[e], s = esrc[e], d = edst[e];
        if (d >= lo && d < hi) atomicAdd(&cnt[d * R_REL + t], 1);
        if (s >= lo && s < hi) atomicAdd(&cnt[(Nn + s) * R_REL + t], 1);
    }
}

// Hierarchical scan, 3 kernels (r5-validated).
__global__ __launch_bounds__(256) void k_scan_part(
    const int* __restrict__ cnt, int* __restrict__ loc,
    int* __restrict__ bsum, int n2)
{
    __shared__ int sh[256];
    const int tid = threadIdx.x;
    const int i0 = blockIdx.x * SCB + tid * 4;
    int v0 = 0, v1 = 0, v2 = 0, v3 = 0;
    if (i0 + 3 < n2) {
        int4 v = *(const int4*)(cnt + i0);
        v0 = v.x; v1 = v.y; v2 = v.z; v3 = v.w;
    } else {
        if (i0 + 0 < n2) v0 = cnt[i0 + 0];
        if (i0 + 1 < n2) v1 = cnt[i0 + 1];
        if (i0 + 2 < n2) v2 = cnt[i0 + 2];
        if (i0 + 3 < n2) v3 = cnt[i0 + 3];
    }
    int t = v0 + v1 + v2 + v3;
    sh[tid] = t;
    __syncthreads();
    for (int o = 1; o < 256; o <<= 1) {
        int x = (tid >= o) ? sh[tid - o] : 0;
        __syncthreads();
        sh[tid] += x;
        __syncthreads();
    }
    int excl = sh[tid] - t;
    if (tid == 255) bsum[blockIdx.x] = sh[255];
    int p0 = excl, p1 = p0 + v0, p2 = p1 + v1, p3 = p2 + v2;
    if (i0 + 3 < n2) {
        *(int4*)(loc + i0) = make_int4(p0, p1, p2, p3);
    } else {
        if (i0 + 0 < n2) loc[i0 + 0] = p0;
        if (i0 + 1 < n2) loc[i0 + 1] = p1;
        if (i0 + 2 < n2) loc[i0 + 2] = p2;
        if (i0 + 3 < n2) loc[i0 + 3] = p3;
    }
}

__global__ __launch_bounds__(256) void k_scan_mid(int* __restrict__ bsum, int nb)
{
    __shared__ int sh[256];
    __shared__ int carry;
    const int tid = threadIdx.x;
    if (tid == 0) carry = 0;
    __syncthreads();
    for (int base = 0; base < nb; base += 256) {
        int i = base + tid;
        int v = (i < nb) ? bsum[i] : 0;
        sh[tid] = v;
        __syncthreads();
        for (int o = 1; o < 256; o <<= 1) {
            int x = (tid >= o) ? sh[tid - o] : 0;
            __syncthreads();
            sh[tid] += x;
            __syncthreads();
        }
        int excl = sh[tid] - v + carry;
        int total = sh[255];
        if (i < nb) bsum[i] = excl;
        __syncthreads();
        if (tid == 0) carry += total;
        __syncthreads();
    }
}

__global__ __launch_bounds__(256) void k_scan_apply(
    const int* __restrict__ loc, const int* __restrict__ bsum,
    int* __restrict__ off, int* __restrict__ cursor, int n2)
{
    const int add = bsum[blockIdx.x];
    const int i0 = blockIdx.x * SCB + threadIdx.x * 4;
    if (i0 + 3 < n2) {
        int4 v = *(const int4*)(loc + i0);
        v.x += add; v.y += add; v.z += add; v.w += add;
        *(int4*)(off + i0) = v;
        *(int4*)(cursor + i0) = v;
    } else {
#pragma unroll
        for (int j = 0; j < 4; j++)
            if (i0 + j < n2) {
                int v = loc[i0 + j] + add;
                off[i0 + j] = v;
                cursor[i0 + j] = v;
            }
    }
}

// rec = (t<<20) | otherNode, via (node,t) cursor -> type-grouped per node.
__global__ __launch_bounds__(256) void k_fill8(
    const int* __restrict__ esrc, const int* __restrict__ edst,
    const int* __restrict__ etype, int* __restrict__ cursor,
    unsigned* __restrict__ rec, int ne, int Nn)
{
    const int oct = blockIdx.x & 7;
    const int slice = blockIdx.x >> 3;
    const int lo = (int)(((long long)oct * Nn) >> 3);
    const int hi = (int)(((long long)(oct + 1) * Nn) >> 3);
    for (int e = slice * 256 + threadIdx.x; e < ne; e += NSLICE * 256) {
        int t = etype[e], s = esrc[e], d = edst[e];
        if (d >= lo && d < hi) {
            int p = atomicAdd(&cursor[d * R_REL + t], 1);
            rec[p] = ((unsigned)t << 20) | (unsigned)s;   // fwd msg into d
        }
        if (s >= lo && s < hi) {
            int p2 = atomicAdd(&cursor[(Nn + s) * R_REL + t], 1);
            rec[p2] = ((unsigned)t << 20) | (unsigned)d;  // bwd msg into s
        }
    }
}

// Fused aggregate+GEMM. Block = 16 nodes, 4 waves, 4 blocks/CU. Per dir:
//  - wave zeroes its 4 Mt rows (wave-private)
//  - bounds for 4 nodes x 9 types prefetched lane-spread; degS from same
//  - wave streams its 4 nodes' records as ONE contiguous range, 8-deep
//    batches: 1 lane-strided rec load + readlane -> 8 row gathers in
//    flight; per record an INDEPENDENT bf16 LDS RMW (ds_read_b32 ->
//    add -> ds_write_b32, conflict-free) -- no register carry chain.
//    node = 3 scalar compares of record index vs boundaries.
//  - barrier; MFMA acc += Mt @ W[dir] (swapped operands); barrier.
// Epilogue: + deg_t*b_t both dirs, single fp32 out store.
__global__ __launch_bounds__(256, 4) void fused_rgcn(
    const unsigned short* __restrict__ Hbf, const unsigned short* __restrict__ Wt,
    const float* __restrict__ B18,
    const int* __restrict__ off3, const int* __restrict__ cur3,
    const unsigned* __restrict__ rec,
    float* __restrict__ out, int Nn)
{
    __shared__ __align__(16) unsigned short Mt[TN][MT_P];
    __shared__ float degS[2][TN][R_REL];

    const int tid = threadIdx.x;
    const int lane = tid & 63;
    const int w = tid >> 6;             // wave id; col slice w*32..w*32+31
    const int lr = lane & 15;
    const int lg = lane >> 4;
    const int n0 = blockIdx.x * TN;

    const short8v* wt8 = (const short8v*)Wt;

    f32x4 acc[2];
    acc[0] = (f32x4){0.f, 0.f, 0.f, 0.f};
    acc[1] = (f32x4){0.f, 0.f, 0.f, 0.f};

#define RMW(rk, vk, idx)                                                      \
    {                                                                         \
        int _t = (rk) >> 20;                                                  \
        int _nd = ((idx) >= s1) + ((idx) >= s2) + ((idx) >= s3);              \
        unsigned* _mp = (unsigned*)(&Mt[w * 4 + _nd][_t * E_DIM]) + lane;     \
        unsigned _u = *_mp;                                                   \
        float _mx = bf2f((unsigned short)(_u & 0xFFFF)) + bf2f((vk).x);       \
        float _my = bf2f((unsigned short)(_u >> 16)) + bf2f((vk).y);          \
        *_mp = ((unsigned)f2bf(_my) << 16) | (unsigned)f2bf(_mx);             \
    }

#pragma unroll 1
    for (int dir = 0; dir < 2; dir++) {
        // Zero this wave's Mt rows (1152 used ushorts = 144 b128 per row).
        const short8v z8 = (short8v){0, 0, 0, 0, 0, 0, 0, 0};
#pragma unroll
        for (int rr = 0; rr < 4; rr++) {
            int row = w * 4 + rr;
            *(short8v*)(&Mt[row][(size_t)lane * 8]) = z8;
            *(short8v*)(&Mt[row][(size_t)(lane + 64) * 8]) = z8;
            if (lane < 16) *(short8v*)(&Mt[row][(size_t)(lane + 128) * 8]) = z8;
        }

        // Prefetch bounds: lane = jj*16 + tt (jj = node-in-wave, tt = type).
        const int jj = lg, tt = lr;
        const int gnode_j = n0 + w * 4 + jj;
        int blo = 0x7F000000, bhi = 0x7F000000;
        if (gnode_j < Nn && tt < R_REL) {
            size_t sb = ((size_t)(dir ? (Nn + gnode_j) : gnode_j)) * R_REL + tt;
            blo = off3[sb];
            bhi = cur3[sb];
            degS[dir][w * 4 + jj][tt] = (float)(bhi - blo);
        }

        const int nvalid = min(4, max(0, Nn - (n0 + w * 4)));
        const int st = __shfl(blo, 0);
        const int en = (nvalid > 0) ? __shfl(bhi, (nvalid - 1) * 16 + 8) : -1;
        const int s1 = __shfl(blo, 16);
        const int s2 = __shfl(blo, 32);
        const int s3 = __shfl(blo, 48);

        int i = st;
        for (; i + 8 <= en; i += 8) {
            unsigned rv = rec[i + (lane & 7)];           // 8 recs, one load
            int r0 = __builtin_amdgcn_readlane(rv, 0);
            int r1 = __builtin_amdgcn_readlane(rv, 1);
            int r2 = __builtin_amdgcn_readlane(rv, 2);
            int r3 = __builtin_amdgcn_readlane(rv, 3);
            int r4 = __builtin_amdgcn_readlane(rv, 4);
            int r5 = __builtin_amdgcn_readlane(rv, 5);
            int r6 = __builtin_amdgcn_readlane(rv, 6);
            int r7 = __builtin_amdgcn_readlane(rv, 7);
            ushort2 v0 = *(const ushort2*)(Hbf + (size_t)(r0 & 0xFFFFF) * E_DIM + 2 * lane);
            ushort2 v1 = *(const ushort2*)(Hbf + (size_t)(r1 & 0xFFFFF) * E_DIM + 2 * lane);
            ushort2 v2 = *(const ushort2*)(Hbf + (size_t)(r2 & 0xFFFFF) * E_DIM + 2 * lane);
            ushort2 v3 = *(const ushort2*)(Hbf + (size_t)(r3 & 0xFFFFF) * E_DIM + 2 * lane);
            ushort2 v4 = *(const ushort2*)(Hbf + (size_t)(r4 & 0xFFFFF) * E_DIM + 2 * lane);
            ushort2 v5 = *(const ushort2*)(Hbf + (size_t)(r5 & 0xFFFFF) * E_DIM + 2 * lane);
            ushort2 v6 = *(const ushort2*)(Hbf + (size_t)(r6 & 0xFFFFF) * E_DIM + 2 * lane);
            ushort2 v7 = *(const ushort2*)(Hbf + (size_t)(r7 & 0xFFFFF) * E_DIM + 2 * lane);
            RMW(r0, v0, i + 0);
            RMW(r1, v1, i + 1);
            RMW(r2, v2, i + 2);
            RMW(r3, v3, i + 3);
            RMW(r4, v4, i + 4);
            RMW(r5, v5, i + 5);
            RMW(r6, v6, i + 6);
            RMW(r7, v7, i + 7);
        }
        for (; i < en; i++) {
            int rk = __builtin_amdgcn_readfirstlane((int)rec[i]);
            ushort2 vk = *(const ushort2*)(Hbf + (size_t)(rk & 0xFFFFF) * E_DIM + 2 * lane);
            RMW(rk, vk, i);
        }
        __syncthreads();

        // ---- GEMM: acc += Mt @ W[dir group] ----
#pragma unroll 1
        for (int q = 0; q < R_REL; q++) {
            const int rel = dir * R_REL + q;
#pragma unroll
            for (int s = 0; s < 4; s++) {
                short8v b0 = wt8[(size_t)((((rel * 4 + w) * 4 + s) * 2 + 0) * 64) + lane];
                short8v b1 = wt8[(size_t)((((rel * 4 + w) * 4 + s) * 2 + 1) * 64) + lane];
                short8v a = *(const short8v*)(&Mt[lr][q * E_DIM + s * 32 + lg * 8]);
                acc[0] = __builtin_amdgcn_mfma_f32_16x16x32_bf16(b0, a, acc[0], 0, 0, 0);
                acc[1] = __builtin_amdgcn_mfma_f32_16x16x32_bf16(b1, a, acc[1], 0, 0, 0);
            }
        }
        __syncthreads();   // before next dir overwrites Mt
    }
#undef RMW

    // ---- epilogue: bias (deg_t * b_t) + store ----
    const int gnode = n0 + lr;
    if (gnode >= Nn) return;
#pragma unroll 1
    for (int dir = 0; dir < 2; dir++) {
#pragma unroll 1
        for (int t = 0; t < R_REL; t++) {
            float dg = degS[dir][lr][t];
            if (dg != 0.f) {
                const float* brow = B18 + (size_t)(dir * R_REL + t) * E_DIM + w * 32 + lg * 4;
                float4 b0 = *(const float4*)(brow);
                float4 b1 = *(const float4*)(brow + 16);
                acc[0][0] += dg * b0.x; acc[0][1] += dg * b0.y;
                acc[0][2] += dg * b0.z; acc[0][3] += dg * b0.w;
                acc[1][0] += dg * b1.x; acc[1][1] += dg * b1.y;
                acc[1][2] += dg * b1.z; acc[1][3] += dg * b1.w;
            }
        }
    }
    float* po = out + (size_t)gnode * E_DIM + w * 32 + lg * 4;
    *(float4*)po = make_float4(acc[0][0], acc[0][1], acc[0][2], acc[0][3]);
    *(float4*)(po + 16) = make_float4(acc[1][0], acc[1][1], acc[1][2], acc[1][3]);
}

// ---------- zero-workspace fallback (round-1, validated) ----------

__global__ __launch_bounds__(128) void direct_edge(
    const int* __restrict__ esrc, const int* __restrict__ edst,
    const int* __restrict__ etype,
    const float* __restrict__ H, const float* __restrict__ W2,
    const float* __restrict__ B2, float* __restrict__ out, int ne)
{
    __shared__ float hs[E_DIM];
    __shared__ float hd[E_DIM];
    int e = blockIdx.x;
    if (e >= ne) return;
    int t = etype[e], s = esrc[e], d = edst[e];
    int c = threadIdx.x;
    hs[c] = H[(size_t)s * E_DIM + c];
    hd[c] = H[(size_t)d * E_DIM + c];
    __syncthreads();
    const float* Wf = W2 + (size_t)t * E_DIM * E_DIM;
    const float* Wb = W2 + (size_t)(t + R_REL) * E_DIM * E_DIM;
    float accf = B2[(size_t)t * E_DIM + c];
    float accb = B2[(size_t)(t + R_REL) * E_DIM + c];
#pragma unroll 8
    for (int k = 0; k < E_DIM; k++) {
        accf += hs[k] * Wf[(size_t)k * E_DIM + c];
        accb += hd[k] * Wb[(size_t)k * E_DIM + c];
    }
    atomicAdd(&out[(size_t)d * E_DIM + c], accf);
    atomicAdd(&out[(size_t)s * E_DIM + c], accb);
}

extern "C" void kernel_launch(void* const* d_in, const int* in_sizes, int n_in,
                              void* d_out, int out_size, void* d_ws, size_t ws_size,
                              hipStream_t stream) {
    const int* edge_index = (const int*)d_in[0];   // [2][NE]
    const int* edge_type  = (const int*)d_in[1];   // [NE]
    const float* emb      = (const float*)d_in[2]; // [N][128]
    const float* weights  = (const float*)d_in[3]; // [L][18][128][128]
    const float* biases   = (const float*)d_in[4]; // [L][18][128]
    float* out = (float*)d_out;

    const int NE = in_sizes[1];
    const int Nn = in_sizes[2] / E_DIM;
    const int L  = in_sizes[3] / (2 * R_REL * E_DIM * E_DIM);

    const float* W2 = weights + (size_t)(L - 1) * 2 * R_REL * E_DIM * E_DIM;
    const float* B2 = biases  + (size_t)(L - 1) * 2 * R_REL * E_DIM;

    const int* esrc = edge_index;
    const int* edst = edge_index + NE;

    const int n3 = 2 * Nn * R_REL;                 // (node,dir,type) segments
    const int nb3 = (n3 + SCB - 1) / SCB;

    auto al = [](size_t x) { return (x + 255) & ~(size_t)255; };
    const size_t hbfBytes = al((size_t)Nn * E_DIM * 2);
    const size_t wtBytes  = al((size_t)2 * R_REL * E_DIM * E_DIM * 2);
    const size_t offBytes = al((size_t)n3 * 4);
    const size_t curBytes = al((size_t)n3 * 4);
    const size_t recBytes = al((size_t)2 * NE * 4);
    const size_t bsBytes  = al((size_t)nb3 * 4);
    const size_t need = hbfBytes + wtBytes + offBytes + curBytes + recBytes + bsBytes;

    if (ws_size >= need && Nn < (1 << 20)) {
        char* p = (char*)d_ws;
        unsigned short* Hbf = (unsigned short*)p;        p += hbfBytes;
        unsigned short* Wt  = (unsigned short*)p;        p += wtBytes;
        int* off3           = (int*)p;                   p += offBytes;
        int* cur3           = (int*)p;                   p += curBytes;
        unsigned* rec       = (unsigned*)p;              p += recBytes;
        int* bsum           = (int*)p;

        const long total8 = (long)Nn * (E_DIM / 8);
        const int hblocks = (int)((total8 + 255) / 256);

        hipMemsetAsync(off3, 0, (size_t)n3 * 4, stream);
        prep<<<18 + hblocks, 256, 0, stream>>>(emb, W2, Hbf, Wt, total8);
        k_count8<<<8 * NSLICE, 256, 0, stream>>>(esrc, edst, edge_type, off3, NE, Nn);
        k_scan_part<<<nb3, 256, 0, stream>>>(off3, cur3, bsum, n3);
        k_scan_mid<<<1, 256, 0, stream>>>(bsum, nb3);
        k_scan_apply<<<nb3, 256, 0, stream>>>(cur3, bsum, off3, cur3, n3);
        k_fill8<<<8 * NSLICE, 256, 0, stream>>>(esrc, edst, edge_type,
                                                cur3, rec, NE, Nn);

        fused_rgcn<<<(Nn + TN - 1) / TN, 256, 0, stream>>>(
            Hbf, Wt, B2, off3, cur3, rec, out, Nn);
        return;
    }

    // Fallback: direct per-edge GEMV with atomics.
    hipMemsetAsync(d_out, 0, (size_t)Nn * E_DIM * sizeof(float), stream);
    direct_edge<<<NE, 128, 0, stream>>>(esrc, edst, edge_type, emb, W2, B2, out, NE);
}